// Round 9
// baseline (358.200 us; speedup 1.0000x reference)
//
#include <hip/hip_runtime.h>
#include <hip/hip_fp16.h>

// Problem constants
#define CDIM 1280
#define LQ 1024
#define NH 20
#define BANKN 40
#define ALPHA_SC 0.48f

typedef __bf16 bf16x8 __attribute__((ext_vector_type(8)));
typedef float f32x4 __attribute__((ext_vector_type(4)));
typedef unsigned short u16;
typedef unsigned int u32;

__device__ __forceinline__ u16 f2bf(float f) {
  union { float f; u32 u; } v; v.f = f;
  u32 r = v.u + 0x7fffu + ((v.u >> 16) & 1u);
  return (u16)(r >> 16);
}

__device__ __forceinline__ void async16(void* lds, const void* g) {
  __builtin_amdgcn_global_load_lds(
      (const __attribute__((address_space(1))) unsigned int*)g,
      (__attribute__((address_space(3))) unsigned int*)lds,
      16, 0, 0);
}

// ---------- prep: fp32 -> bf16 convert of hidden_states ----------
__global__ __launch_bounds__(256) void k_convx(const float* __restrict__ X,
                                               u16* __restrict__ Xb) {
  int i = (blockIdx.x * 256 + threadIdx.x) * 4;
  float4 f = *(const float4*)(X + i);
  u32 lo = (u32)f2bf(f.x) | ((u32)f2bf(f.y) << 16);
  u32 hi = (u32)f2bf(f.z) | ((u32)f2bf(f.w) << 16);
  *(uint2*)(Xb + i) = make_uint2(lo, hi);
}

// ---------- prep: transpose+convert weights: Wt[n][k] = W[k][n] ----------
__global__ __launch_bounds__(256) void k_wtrans(const float* __restrict__ Wq,
                                                const float* __restrict__ Wk,
                                                const float* __restrict__ Wv,
                                                const float* __restrict__ Wo,
                                                u16* __restrict__ Wtqkv,
                                                u16* __restrict__ Wot) {
  __shared__ float tile[32][33];
  int z = blockIdx.z;
  const float* src = (z == 0) ? Wq : (z == 1) ? Wk : (z == 2) ? Wv : Wo;
  u16* dst = (z < 3) ? (Wtqkv + (size_t)z * CDIM * CDIM) : Wot;
  int tx = threadIdx.x, ty = threadIdx.y;
  int n0 = blockIdx.x * 32, k0 = blockIdx.y * 32;
#pragma unroll
  for (int j = 0; j < 4; ++j)
    tile[ty + 8 * j][tx] = src[(size_t)(k0 + ty + 8 * j) * CDIM + n0 + tx];
  __syncthreads();
#pragma unroll
  for (int j = 0; j < 4; ++j)
    dst[(size_t)(n0 + ty + 8 * j) * CDIM + k0 + tx] = f2bf(tile[tx][ty + 8 * j]);
}

// ---------- prep: bank KV fp16-round + 2x2 avg-pool + alpha ----------
__global__ __launch_bounds__(256) void k_pool(const float* __restrict__ Kbg,
                                              const float* __restrict__ Vbg,
                                              u16* __restrict__ Kp,
                                              u16* __restrict__ Vpt) {
  int bank = blockIdx.x, seg = blockIdx.y;
  int tid = threadIdx.x;
#pragma unroll
  for (int j = 0; j < 16; ++j) {
    int idx = j * 256 + tid;
    int d = idx & 63, tl = idx >> 6;
    int t = seg * 64 + tl;
    int r = t >> 4, c = t & 15;
    int tok = (r * 2) * 32 + c * 2;
    const float* kb = Kbg + ((size_t)bank * 1024 + tok) * 64 + d;
    float k0 = __half2float(__float2half(kb[0]));
    float k1 = __half2float(__float2half(kb[64]));
    float k2 = __half2float(__float2half(kb[32 * 64]));
    float k3 = __half2float(__float2half(kb[33 * 64]));
    Kp[((size_t)bank * 256 + t) * 64 + d] = f2bf((k0 + k1 + k2 + k3) * 0.25f * ALPHA_SC);
  }
#pragma unroll
  for (int j = 0; j < 16; ++j) {
    int idx = j * 256 + tid;
    int tl = idx & 63, d = idx >> 6;
    int t = seg * 64 + tl;
    int r = t >> 4, c = t & 15;
    int tok = (r * 2) * 32 + c * 2;
    const float* vb = Vbg + ((size_t)bank * 1024 + tok) * 64 + d;
    float v0 = __half2float(__float2half(vb[0]));
    float v1 = __half2float(__float2half(vb[64]));
    float v2 = __half2float(__float2half(vb[32 * 64]));
    float v3 = __half2float(__float2half(vb[33 * 64]));
    Vpt[((size_t)bank * 64 + d) * 256 + t] = f2bf((v0 + v1 + v2 + v3) * 0.25f * ALPHA_SC);
  }
}

// ---------- QKV GEMM: Xb[4096][1280] @ {Wq,Wk,Wv}^T -> qh/kh [80][1024][64], vT [80][64][1024] ----------
// m97 structure: BK=32, global_load_lds width=16, XCD swizzle. q is pre-scaled by 0.125 (exact in bf16).
__global__ __launch_bounds__(256) void k_gemm_qkv(const u16* __restrict__ A,
                                                  const u16* __restrict__ Bt,
                                                  u16* __restrict__ qh,
                                                  u16* __restrict__ kh,
                                                  u16* __restrict__ vT) {
  __shared__ __align__(16) u16 smem[8704];  // K-loop: As[4096]+Bs[4096]; epilogue alias OS[64*136]
  u16* As = smem;
  u16* Bs = smem + 4096;
  u16* OS = smem;

  int lid = blockIdx.x;            // 0..959
  int s = lid & 7, g = lid >> 3;   // XCD swizzle: same-XCD blocks share A-panels
  int blkM = s * 4 + (g & 3);      // 0..31
  int blkN = g >> 2;               // 0..29
  int tid = threadIdx.x;
  int lane = tid & 63, quad = lane >> 4, li = lane & 15;
  int w = tid >> 6;
  int wr = w >> 1, wc = w & 1;
  int lrow = lane >> 2, lch = lane & 3;

  f32x4 acc[4][4];
#pragma unroll
  for (int i = 0; i < 4; ++i)
#pragma unroll
    for (int j = 0; j < 4; ++j)
#pragma unroll
      for (int e = 0; e < 4; ++e) acc[i][j][e] = 0.f;

  const u16* Ab = A + (size_t)blkM * 128 * CDIM;
  const u16* Bb = Bt + (size_t)blkN * 128 * CDIM;

  for (int kt = 0; kt < 40; ++kt) {
    __syncthreads();  // prior iter's ds_reads done before DMA overwrite
#pragma unroll
    for (int p = 0; p < 2; ++p) {
      int row = p * 64 + w * 16;  // wave-uniform LDS base
      async16(As + row * 32, Ab + (size_t)(row + lrow) * CDIM + kt * 32 + lch * 8);
      async16(Bs + row * 32, Bb + (size_t)(row + lrow) * CDIM + kt * 32 + lch * 8);
    }
    __syncthreads();  // vmcnt(0) drain makes DMA writes visible
    bf16x8 af[4], bfr[4];
#pragma unroll
    for (int mt = 0; mt < 4; ++mt)
      af[mt] = *(const bf16x8*)(As + (wr * 64 + mt * 16 + li) * 32 + quad * 8);
#pragma unroll
    for (int nt = 0; nt < 4; ++nt)
      bfr[nt] = *(const bf16x8*)(Bs + (wc * 64 + nt * 16 + li) * 32 + quad * 8);
#pragma unroll
    for (int mt = 0; mt < 4; ++mt)
#pragma unroll
      for (int nt = 0; nt < 4; ++nt)
        acc[mt][nt] = __builtin_amdgcn_mfma_f32_16x16x32_bf16(af[mt], bfr[nt], acc[mt][nt], 0, 0, 0);
  }

  int which = blkN / 10;  // 0=q 1=k 2=v
  float osc = (which == 0) ? 0.125f : 1.0f;  // fold 1/sqrt(Dh) into q (exact: power of 2)
  int cbase = (blkN % 10) * 128;
  int b = blkM >> 3;  // 128 rows lie within one batch
#pragma unroll
  for (int p = 0; p < 2; ++p) {
    __syncthreads();
    if (wr == p) {
#pragma unroll
      for (int mt = 0; mt < 4; ++mt)
#pragma unroll
        for (int nt = 0; nt < 4; ++nt)
#pragma unroll
          for (int r = 0; r < 4; ++r)
            OS[(mt * 16 + quad * 4 + r) * 136 + wc * 64 + nt * 16 + li] = f2bf(acc[mt][nt][r] * osc);
    }
    __syncthreads();
    if (which < 2) {
      u16* dst = (which == 0) ? qh : kh;
#pragma unroll
      for (int j = 0; j < 4; ++j) {
        int linear = j * 256 + tid;
        int row = linear >> 4, ci = linear & 15;
        int grow = blkM * 128 + p * 64 + row;
        int l = grow & 1023;
        int c = cbase + ci * 8;
        int h = c >> 6, dd = c & 63;
        uint4 val = *(const uint4*)(&OS[row * 136 + ci * 8]);
        *(uint4*)(&dst[(((size_t)(b * NH + h)) * LQ + l) * 64 + dd]) = val;
      }
    } else {
      // v: write transposed directly into vT[80][64][1024]
      int vrow = tid >> 1;
      int lhalf = tid & 1;
      int h = (cbase + vrow) >> 6, d = vrow & 63;
      size_t vbase = (((size_t)(b * NH + h)) * 64 + d) * LQ +
                     (blkM & 7) * 128 + p * 64 + lhalf * 32;
#pragma unroll
      for (int c4 = 0; c4 < 4; ++c4) {
        int ll = lhalf * 32 + c4 * 8;
        u32 w0 = (u32)OS[(ll + 0) * 136 + vrow] | ((u32)OS[(ll + 1) * 136 + vrow] << 16);
        u32 w1 = (u32)OS[(ll + 2) * 136 + vrow] | ((u32)OS[(ll + 3) * 136 + vrow] << 16);
        u32 w2 = (u32)OS[(ll + 4) * 136 + vrow] | ((u32)OS[(ll + 5) * 136 + vrow] << 16);
        u32 w3 = (u32)OS[(ll + 6) * 136 + vrow] | ((u32)OS[(ll + 7) * 136 + vrow] << 16);
        *(uint4*)(vT + vbase + c4 * 8) = make_uint4(w0, w1, w2, w3);
      }
    }
  }
}

// ---------- flash attention, transposed-S form ----------
// waves_per_eu(3,4): min=3 -> RA budget ~170 VGPR (no spill; round-8 evidence: needs ~90-120).
// max=4 -> NO LDS padding (round-8's (2,2) padded LDS 45->76 KB, forcing 2 blocks/CU and
// occupancy 17.6%). 44 KB LDS naturally caps at 3 blocks/CU = 12 waves/CU.
__global__ __launch_bounds__(256)
__attribute__((amdgpu_waves_per_eu(3, 4)))
void k_attn(const u16* __restrict__ qh,
            const u16* __restrict__ kh,
            const u16* __restrict__ vT,
            const u16* __restrict__ Kp,
            const u16* __restrict__ Vpt,
            u16* __restrict__ ctx) {
  __shared__ u16 Qs[64 * 72];
  __shared__ u16 Ks[128 * 72];   // epilogue alias: OS[64][72]
  __shared__ u16 Vt[64 * 136];
  u16* OS = Ks;
  int lid = blockIdx.x;            // 0..1279
  int s = lid & 7, g = lid >> 3;   // XCD swizzle
  int bh = g >> 1;
  int qt = ((g & 1) << 3) | s;
  int b = bh / NH, h = bh % NH;
  int tid = threadIdx.x;
  int w = tid >> 6, lane = tid & 63, quad = lane >> 4, li = lane & 15;

  const u16* qb = qh + ((size_t)bh * LQ + qt * 64) * 64;
#pragma unroll
  for (int p = 0; p < 2; ++p) {
    int idx = p * 256 + tid;
    int row = idx >> 3, ch = idx & 7;
    uint4 d4 = *(const uint4*)(qb + row * 64 + ch * 8);
    *(uint4*)(&Qs[row * 72 + ch * 8]) = d4;
  }
  __syncthreads();
  // Q fragments (loop-invariant); used as the B operand of S^T = K·Q^T
  bf16x8 bq0 = *(const bf16x8*)(&Qs[(w * 16 + li) * 72 + quad * 8]);
  bf16x8 bq1 = *(const bf16x8*)(&Qs[(w * 16 + li) * 72 + 32 + quad * 8]);

  f32x4 oacc[4];  // O^T: D[m = d = quad*4+r (+16*dt)][n = q = li]
#pragma unroll
  for (int i = 0; i < 4; ++i)
#pragma unroll
    for (int e = 0; e < 4; ++e) oacc[i][e] = 0.f;
  float m_run = -1e30f, l_run = 0.f;  // per-lane: q = w*16 + li

  int bank = bh % BANKN;
  uint4 kreg[4], vreg[4];
  {
    const u16* kb = kh + (size_t)bh * LQ * 64;
    const u16* vb = vT + (size_t)bh * 64 * LQ;
#pragma unroll
    for (int p = 0; p < 4; ++p) {
      int idx = p * 256 + tid;
      int row = idx >> 3, ch = idx & 7;
      kreg[p] = *(const uint4*)(kb + row * 64 + ch * 8);
    }
#pragma unroll
    for (int p = 0; p < 4; ++p) {
      int idx = p * 256 + tid;
      int row = idx >> 4, ch = idx & 15;
      vreg[p] = *(const uint4*)(vb + (size_t)row * 1024 + ch * 8);
    }
  }

  for (int kt = 0; kt < 10; ++kt) {
    __syncthreads();  // B1: prior iter's Ks(QK) and Vt(PV) reads done
#pragma unroll
    for (int p = 0; p < 4; ++p) {
      int idx = p * 256 + tid;
      int row = idx >> 3, ch = idx & 7;
      *(uint4*)(&Ks[row * 72 + ch * 8]) = kreg[p];
    }
#pragma unroll
    for (int p = 0; p < 4; ++p) {
      int idx = p * 256 + tid;
      int row = idx >> 4, ch = idx & 15;
      *(uint4*)(&Vt[row * 136 + ch * 8]) = vreg[p];
    }
    __syncthreads();  // B2: staging visible

    if (kt < 9) {
      int kn = kt + 1;
      const u16 *kb, *vb;
      int vstride;
      if (kn < 8) {
        kb = kh + ((size_t)bh * LQ + kn * 128) * 64;
        vb = vT + (size_t)bh * 64 * LQ + kn * 128;
        vstride = 1024;
      } else {
        kb = Kp + ((size_t)bank * 256 + (kn - 8) * 128) * 64;
        vb = Vpt + (size_t)bank * 64 * 256 + (kn - 8) * 128;
        vstride = 256;
      }
#pragma unroll
      for (int p = 0; p < 4; ++p) {
        int idx = p * 256 + tid;
        int row = idx >> 3, ch = idx & 7;
        kreg[p] = *(const uint4*)(kb + row * 64 + ch * 8);
      }
#pragma unroll
      for (int p = 0; p < 4; ++p) {
        int idx = p * 256 + tid;
        int row = idx >> 4, ch = idx & 15;
        vreg[p] = *(const uint4*)(vb + (size_t)row * vstride + ch * 8);
      }
    }

    // S^T: lane holds S[q = w*16+li][kt_local = nt*16 + quad*4 + r] (q pre-scaled by 0.125)
    f32x4 sacc[8];
#pragma unroll
    for (int nt = 0; nt < 8; ++nt) {
      bf16x8 k0 = *(const bf16x8*)(&Ks[(nt * 16 + li) * 72 + quad * 8]);
      bf16x8 k1 = *(const bf16x8*)(&Ks[(nt * 16 + li) * 72 + 32 + quad * 8]);
      f32x4 sc;
#pragma unroll
      for (int e = 0; e < 4; ++e) sc[e] = 0.f;
      sc = __builtin_amdgcn_mfma_f32_16x16x32_bf16(k0, bq0, sc, 0, 0, 0);
      sc = __builtin_amdgcn_mfma_f32_16x16x32_bf16(k1, bq1, sc, 0, 0, 0);
      sacc[nt] = sc;
    }

    // online softmax: per-lane scalar state, quad-reduce via 2 shuffles
    float mx = sacc[0][0];
#pragma unroll
    for (int nt = 0; nt < 8; ++nt)
#pragma unroll
      for (int r = 0; r < 4; ++r) mx = fmaxf(mx, sacc[nt][r]);
    mx = fmaxf(mx, __shfl_xor(mx, 16));
    mx = fmaxf(mx, __shfl_xor(mx, 32));
    float mnew = fmaxf(m_run, mx);
    float al = __expf(m_run - mnew);
    m_run = mnew;

    float rsum = 0.f;
    u32 pk[8][2];  // packed bf16 P pairs: pk[nt][h] = (r=2h, r=2h+1)
#pragma unroll
    for (int nt = 0; nt < 8; ++nt) {
      float p0 = __expf(sacc[nt][0] - mnew);
      float p1 = __expf(sacc[nt][1] - mnew);
      float p2 = __expf(sacc[nt][2] - mnew);
      float p3 = __expf(sacc[nt][3] - mnew);
      rsum += (p0 + p1) + (p2 + p3);
      pk[nt][0] = (u32)f2bf(p0) | ((u32)f2bf(p1) << 16);
      pk[nt][1] = (u32)f2bf(p2) | ((u32)f2bf(p3) << 16);
    }
    rsum += __shfl_xor(rsum, 16);
    rsum += __shfl_xor(rsum, 32);
    l_run = l_run * al + rsum;
#pragma unroll
    for (int dt = 0; dt < 4; ++dt)
#pragma unroll
      for (int e = 0; e < 4; ++e) oacc[dt][e] *= al;

    // O^T += Vt · P^T: build P B-frag per 32-k chunk via cross-quad shuffles
    int srcA = ((lane & 16) << 1) + li;  // ((quad&1)*2)*16 + li
    int srcB = srcA + 16;
    bool lowq = (quad < 2);
#pragma unroll
    for (int ks = 0; ks < 4; ++ks) {
      u32 xA0 = __shfl(pk[2 * ks][0], srcA), xA1 = __shfl(pk[2 * ks][1], srcA);
      u32 xB0 = __shfl(pk[2 * ks][0], srcB), xB1 = __shfl(pk[2 * ks][1], srcB);
      u32 yA0 = __shfl(pk[2 * ks + 1][0], srcA), yA1 = __shfl(pk[2 * ks + 1][1], srcA);
      u32 yB0 = __shfl(pk[2 * ks + 1][0], srcB), yB1 = __shfl(pk[2 * ks + 1][1], srcB);
      union { uint4 u; bf16x8 b; } bp;
      bp.u = make_uint4(lowq ? xA0 : yA0, lowq ? xA1 : yA1,
                        lowq ? xB0 : yB0, lowq ? xB1 : yB1);
#pragma unroll
      for (int dt = 0; dt < 4; ++dt) {
        bf16x8 av = *(const bf16x8*)(&Vt[(dt * 16 + li) * 136 + ks * 32 + quad * 8]);
        oacc[dt] = __builtin_amdgcn_mfma_f32_16x16x32_bf16(av, bp.b, oacc[dt], 0, 0, 0);
      }
    }
  }

  // epilogue: O^T[d][q]/l -> stage as OS[q][d] (alias Ks), then coalesced stores
  __syncthreads();  // all waves past final QK reads of Ks
  float inv_l = 1.0f / l_run;
#pragma unroll
  for (int dt = 0; dt < 4; ++dt)
#pragma unroll
    for (int r = 0; r < 4; ++r)
      OS[(w * 16 + li) * 72 + dt * 16 + quad * 4 + r] = f2bf(oacc[dt][r] * inv_l);
  __syncthreads();
#pragma unroll
  for (int j = 0; j < 2; ++j) {
    int linear = j * 256 + tid;
    int row = linear >> 3, ci = linear & 7;
    uint4 val = *(const uint4*)(&OS[row * 72 + ci * 8]);
    *(uint4*)(&ctx[((size_t)b * LQ + qt * 64 + row) * CDIM + h * 64 + ci * 8]) = val;
  }
}

// ---------- output GEMM: ctx[4096][1280] @ Wo + bo -> out fp32 ----------
__global__ __launch_bounds__(256) void k_gemm_out(const u16* __restrict__ A,
                                                  const u16* __restrict__ Bt,
                                                  const float* __restrict__ bias,
                                                  float* __restrict__ out) {
  __shared__ __align__(16) u16 smem[8192];
  u16* As = smem;
  u16* Bs = smem + 4096;

  int lid = blockIdx.x;            // 0..319
  int s = lid & 7, g = lid >> 3;   // 0..39
  int blkM = s * 4 + (g & 3);
  int blkN = g >> 2;               // 0..9
  int tid = threadIdx.x;
  int lane = tid & 63, quad = lane >> 4, li = lane & 15;
  int w = tid >> 6;
  int wr = w >> 1, wc = w & 1;
  int lrow = lane >> 2, lch = lane & 3;

  f32x4 acc[4][4];
#pragma unroll
  for (int i = 0; i < 4; ++i)
#pragma unroll
    for (int j = 0; j < 4; ++j)
#pragma unroll
      for (int e = 0; e < 4; ++e) acc[i][j][e] = 0.f;

  const u16* Ab = A + (size_t)blkM * 128 * CDIM;
  const u16* Bb = Bt + (size_t)blkN * 128 * CDIM;

  for (int kt = 0; kt < 40; ++kt) {
    __syncthreads();
#pragma unroll
    for (int p = 0; p < 2; ++p) {
      int row = p * 64 + w * 16;
      async16(As + row * 32, Ab + (size_t)(row + lrow) * CDIM + kt * 32 + lch * 8);
      async16(Bs + row * 32, Bb + (size_t)(row + lrow) * CDIM + kt * 32 + lch * 8);
    }
    __syncthreads();
    bf16x8 af[4], bfr[4];
#pragma unroll
    for (int mt = 0; mt < 4; ++mt)
      af[mt] = *(const bf16x8*)(As + (wr * 64 + mt * 16 + li) * 32 + quad * 8);
#pragma unroll
    for (int nt = 0; nt < 4; ++nt)
      bfr[nt] = *(const bf16x8*)(Bs + (wc * 64 + nt * 16 + li) * 32 + quad * 8);
#pragma unroll
    for (int mt = 0; mt < 4; ++mt)
#pragma unroll
      for (int nt = 0; nt < 4; ++nt)
        acc[mt][nt] = __builtin_amdgcn_mfma_f32_16x16x32_bf16(af[mt], bfr[nt], acc[mt][nt], 0, 0, 0);
  }

#pragma unroll
  for (int mt = 0; mt < 4; ++mt) {
#pragma unroll
    for (int nt = 0; nt < 4; ++nt) {
#pragma unroll
      for (int r = 0; r < 4; ++r) {
        int row = blkM * 128 + wr * 64 + mt * 16 + quad * 4 + r;
        int col = blkN * 128 + wc * 64 + nt * 16 + li;
        out[(size_t)row * CDIM + col] = acc[mt][nt][r] + bias[col];
      }
    }
  }
}

extern "C" void kernel_launch(void* const* d_in, const int* in_sizes, int n_in,
                              void* d_out, int out_size, void* d_ws, size_t ws_size,
                              hipStream_t stream) {
  const float* X = (const float*)d_in[0];
  const float* Wq = (const float*)d_in[1];
  const float* Wk = (const float*)d_in[2];
  const float* Wv = (const float*)d_in[3];
  const float* Wo = (const float*)d_in[4];
  const float* bo = (const float*)d_in[5];
  const float* Kbg = (const float*)d_in[6];
  const float* Vbg = (const float*)d_in[7];

  char* ws = (char*)d_ws;
  u16* Xb    = (u16*)(ws + 0);          // 4096*1280*2  = 10485760
  u16* Wtqkv = (u16*)(ws + 10485760);   // 3*1280*1280*2 = 9830400
  u16* Wot   = (u16*)(ws + 20316160);   // 1280*1280*2  = 3276800
  u16* qh    = (u16*)(ws + 23592960);   // 80*1024*64*2 = 10485760
  u16* kh    = (u16*)(ws + 34078720);
  u16* vT    = (u16*)(ws + 55050240);
  u16* Kp    = (u16*)(ws + 65536000);   // 40*256*64*2 = 1310720
  u16* Vpt   = (u16*)(ws + 66846720);
  u16* ctx   = (u16*)(ws + 68157440);   // ends 78643200
  if (ws_size < 78643200) return;

  float* out = (float*)d_out;

  k_convx<<<5120, 256, 0, stream>>>(X, Xb);
  k_wtrans<<<dim3(40, 40, 4), dim3(32, 8), 0, stream>>>(Wq, Wk, Wv, Wo, Wtqkv, Wot);
  k_pool<<<dim3(40, 4), 256, 0, stream>>>(Kbg, Vbg, Kp, Vpt);
  k_gemm_qkv<<<960, 256, 0, stream>>>(Xb, Wtqkv, qh, kh, vT);
  k_attn<<<1280, 256, 0, stream>>>(qh, kh, vT, Kp, Vpt, ctx);
  k_gemm_out<<<320, 256, 0, stream>>>(ctx, Wot, bo, out);
}

// Round 10
// 325.754 us; speedup vs baseline: 1.0996x; 1.0996x over previous
//
#include <hip/hip_runtime.h>
#include <hip/hip_fp16.h>

// Problem constants
#define CDIM 1280
#define LQ 1024
#define NH 20
#define BANKN 40
#define ALPHA_SC 0.48f

typedef __bf16 bf16x8 __attribute__((ext_vector_type(8)));
typedef float f32x4 __attribute__((ext_vector_type(4)));
typedef unsigned short u16;
typedef unsigned int u32;

__device__ __forceinline__ u16 f2bf(float f) {
  union { float f; u32 u; } v; v.f = f;
  u32 r = v.u + 0x7fffu + ((v.u >> 16) & 1u);
  return (u16)(r >> 16);
}

__device__ __forceinline__ void async16(void* lds, const void* g) {
  __builtin_amdgcn_global_load_lds(
      (const __attribute__((address_space(1))) unsigned int*)g,
      (__attribute__((address_space(3))) unsigned int*)lds,
      16, 0, 0);
}

// ---------- prep: fp32 -> bf16 convert of hidden_states ----------
__global__ __launch_bounds__(256) void k_convx(const float* __restrict__ X,
                                               u16* __restrict__ Xb) {
  int i = (blockIdx.x * 256 + threadIdx.x) * 4;
  float4 f = *(const float4*)(X + i);
  u32 lo = (u32)f2bf(f.x) | ((u32)f2bf(f.y) << 16);
  u32 hi = (u32)f2bf(f.z) | ((u32)f2bf(f.w) << 16);
  *(uint2*)(Xb + i) = make_uint2(lo, hi);
}

// ---------- prep: transpose+convert weights: Wt[n][k] = W[k][n] ----------
__global__ __launch_bounds__(256) void k_wtrans(const float* __restrict__ Wq,
                                                const float* __restrict__ Wk,
                                                const float* __restrict__ Wv,
                                                const float* __restrict__ Wo,
                                                u16* __restrict__ Wtqkv,
                                                u16* __restrict__ Wot) {
  __shared__ float tile[32][33];
  int z = blockIdx.z;
  const float* src = (z == 0) ? Wq : (z == 1) ? Wk : (z == 2) ? Wv : Wo;
  u16* dst = (z < 3) ? (Wtqkv + (size_t)z * CDIM * CDIM) : Wot;
  int tx = threadIdx.x, ty = threadIdx.y;
  int n0 = blockIdx.x * 32, k0 = blockIdx.y * 32;
#pragma unroll
  for (int j = 0; j < 4; ++j)
    tile[ty + 8 * j][tx] = src[(size_t)(k0 + ty + 8 * j) * CDIM + n0 + tx];
  __syncthreads();
#pragma unroll
  for (int j = 0; j < 4; ++j)
    dst[(size_t)(n0 + ty + 8 * j) * CDIM + k0 + tx] = f2bf(tile[tx][ty + 8 * j]);
}

// ---------- prep: bank KV fp16-round + 2x2 avg-pool + alpha ----------
__global__ __launch_bounds__(256) void k_pool(const float* __restrict__ Kbg,
                                              const float* __restrict__ Vbg,
                                              u16* __restrict__ Kp,
                                              u16* __restrict__ Vpt) {
  int bank = blockIdx.x, seg = blockIdx.y;
  int tid = threadIdx.x;
#pragma unroll
  for (int j = 0; j < 16; ++j) {
    int idx = j * 256 + tid;
    int d = idx & 63, tl = idx >> 6;
    int t = seg * 64 + tl;
    int r = t >> 4, c = t & 15;
    int tok = (r * 2) * 32 + c * 2;
    const float* kb = Kbg + ((size_t)bank * 1024 + tok) * 64 + d;
    float k0 = __half2float(__float2half(kb[0]));
    float k1 = __half2float(__float2half(kb[64]));
    float k2 = __half2float(__float2half(kb[32 * 64]));
    float k3 = __half2float(__float2half(kb[33 * 64]));
    Kp[((size_t)bank * 256 + t) * 64 + d] = f2bf((k0 + k1 + k2 + k3) * 0.25f * ALPHA_SC);
  }
#pragma unroll
  for (int j = 0; j < 16; ++j) {
    int idx = j * 256 + tid;
    int tl = idx & 63, d = idx >> 6;
    int t = seg * 64 + tl;
    int r = t >> 4, c = t & 15;
    int tok = (r * 2) * 32 + c * 2;
    const float* vb = Vbg + ((size_t)bank * 1024 + tok) * 64 + d;
    float v0 = __half2float(__float2half(vb[0]));
    float v1 = __half2float(__float2half(vb[64]));
    float v2 = __half2float(__float2half(vb[32 * 64]));
    float v3 = __half2float(__float2half(vb[33 * 64]));
    Vpt[((size_t)bank * 64 + d) * 256 + t] = f2bf((v0 + v1 + v2 + v3) * 0.25f * ALPHA_SC);
  }
}

// ---------- QKV GEMM: Xb[4096][1280] @ {Wq,Wk,Wv}^T -> qh/kh [80][1024][64], vT [80][64][1024] ----------
// m97 structure: BK=32, global_load_lds width=16, XCD swizzle. q is pre-scaled by 0.125 (exact in bf16).
__global__ __launch_bounds__(256) void k_gemm_qkv(const u16* __restrict__ A,
                                                  const u16* __restrict__ Bt,
                                                  u16* __restrict__ qh,
                                                  u16* __restrict__ kh,
                                                  u16* __restrict__ vT) {
  __shared__ __align__(16) u16 smem[8704];  // K-loop: As[4096]+Bs[4096]; epilogue alias OS[64*136]
  u16* As = smem;
  u16* Bs = smem + 4096;
  u16* OS = smem;

  int lid = blockIdx.x;            // 0..959
  int s = lid & 7, g = lid >> 3;   // XCD swizzle: same-XCD blocks share A-panels
  int blkM = s * 4 + (g & 3);      // 0..31
  int blkN = g >> 2;               // 0..29
  int tid = threadIdx.x;
  int lane = tid & 63, quad = lane >> 4, li = lane & 15;
  int w = tid >> 6;
  int wr = w >> 1, wc = w & 1;
  int lrow = lane >> 2, lch = lane & 3;

  f32x4 acc[4][4];
#pragma unroll
  for (int i = 0; i < 4; ++i)
#pragma unroll
    for (int j = 0; j < 4; ++j)
#pragma unroll
      for (int e = 0; e < 4; ++e) acc[i][j][e] = 0.f;

  const u16* Ab = A + (size_t)blkM * 128 * CDIM;
  const u16* Bb = Bt + (size_t)blkN * 128 * CDIM;

  for (int kt = 0; kt < 40; ++kt) {
    __syncthreads();  // prior iter's ds_reads done before DMA overwrite
#pragma unroll
    for (int p = 0; p < 2; ++p) {
      int row = p * 64 + w * 16;  // wave-uniform LDS base
      async16(As + row * 32, Ab + (size_t)(row + lrow) * CDIM + kt * 32 + lch * 8);
      async16(Bs + row * 32, Bb + (size_t)(row + lrow) * CDIM + kt * 32 + lch * 8);
    }
    __syncthreads();  // vmcnt(0) drain makes DMA writes visible
    bf16x8 af[4], bfr[4];
#pragma unroll
    for (int mt = 0; mt < 4; ++mt)
      af[mt] = *(const bf16x8*)(As + (wr * 64 + mt * 16 + li) * 32 + quad * 8);
#pragma unroll
    for (int nt = 0; nt < 4; ++nt)
      bfr[nt] = *(const bf16x8*)(Bs + (wc * 64 + nt * 16 + li) * 32 + quad * 8);
#pragma unroll
    for (int mt = 0; mt < 4; ++mt)
#pragma unroll
      for (int nt = 0; nt < 4; ++nt)
        acc[mt][nt] = __builtin_amdgcn_mfma_f32_16x16x32_bf16(af[mt], bfr[nt], acc[mt][nt], 0, 0, 0);
  }

  int which = blkN / 10;  // 0=q 1=k 2=v
  float osc = (which == 0) ? 0.125f : 1.0f;  // fold 1/sqrt(Dh) into q (exact: power of 2)
  int cbase = (blkN % 10) * 128;
  int b = blkM >> 3;  // 128 rows lie within one batch
#pragma unroll
  for (int p = 0; p < 2; ++p) {
    __syncthreads();
    if (wr == p) {
#pragma unroll
      for (int mt = 0; mt < 4; ++mt)
#pragma unroll
        for (int nt = 0; nt < 4; ++nt)
#pragma unroll
          for (int r = 0; r < 4; ++r)
            OS[(mt * 16 + quad * 4 + r) * 136 + wc * 64 + nt * 16 + li] = f2bf(acc[mt][nt][r] * osc);
    }
    __syncthreads();
    if (which < 2) {
      u16* dst = (which == 0) ? qh : kh;
#pragma unroll
      for (int j = 0; j < 4; ++j) {
        int linear = j * 256 + tid;
        int row = linear >> 4, ci = linear & 15;
        int grow = blkM * 128 + p * 64 + row;
        int l = grow & 1023;
        int c = cbase + ci * 8;
        int h = c >> 6, dd = c & 63;
        uint4 val = *(const uint4*)(&OS[row * 136 + ci * 8]);
        *(uint4*)(&dst[(((size_t)(b * NH + h)) * LQ + l) * 64 + dd]) = val;
      }
    } else {
      // v: write transposed directly into vT[80][64][1024]
      int vrow = tid >> 1;
      int lhalf = tid & 1;
      int h = (cbase + vrow) >> 6, d = vrow & 63;
      size_t vbase = (((size_t)(b * NH + h)) * 64 + d) * LQ +
                     (blkM & 7) * 128 + p * 64 + lhalf * 32;
#pragma unroll
      for (int c4 = 0; c4 < 4; ++c4) {
        int ll = lhalf * 32 + c4 * 8;
        u32 w0 = (u32)OS[(ll + 0) * 136 + vrow] | ((u32)OS[(ll + 1) * 136 + vrow] << 16);
        u32 w1 = (u32)OS[(ll + 2) * 136 + vrow] | ((u32)OS[(ll + 3) * 136 + vrow] << 16);
        u32 w2 = (u32)OS[(ll + 4) * 136 + vrow] | ((u32)OS[(ll + 5) * 136 + vrow] << 16);
        u32 w3 = (u32)OS[(ll + 6) * 136 + vrow] | ((u32)OS[(ll + 7) * 136 + vrow] << 16);
        *(uint4*)(vT + vbase + c4 * 8) = make_uint4(w0, w1, w2, w3);
      }
    }
  }
}

// ---------- flash attention, transposed-S form, 128-q blocks (512 thr / 8 waves) ----------
// Round-9 lesson: only a PINNED waves_per_eu(N,N) controls the RA. (4,4) -> 128 VGPR
// budget (no spill; needs ~110) and 16 waves/CU at 2 blocks/CU (54 KB LDS).
// 2x MFMA per staged K/V tile vs the 64-q version; kreg/vreg prefetch halves.
__global__ __launch_bounds__(512)
__attribute__((amdgpu_waves_per_eu(4, 4)))
void k_attn(const u16* __restrict__ qh,
            const u16* __restrict__ kh,
            const u16* __restrict__ vT,
            const u16* __restrict__ Kp,
            const u16* __restrict__ Vpt,
            u16* __restrict__ ctx) {
  __shared__ u16 Qs[128 * 72];   // Q tile; epilogue alias OS[128][72]
  __shared__ u16 Ks[128 * 72];
  __shared__ u16 Vt[64 * 136];
  u16* OS = Qs;
  int lid = blockIdx.x;            // 0..639
  int s = lid & 7, g = lid >> 3;   // XCD swizzle: XCD s owns bh range [s*10, s*10+10)
  int bh = s * 10 + (g >> 3);
  int qt8 = g & 7;                 // 128-row q tile
  int b = bh / NH, h = bh % NH;
  int tid = threadIdx.x;
  int w = tid >> 6, lane = tid & 63, quad = lane >> 4, li = lane & 15;

  const u16* qb = qh + ((size_t)bh * LQ + qt8 * 128) * 64;
#pragma unroll
  for (int p = 0; p < 2; ++p) {
    int idx = p * 512 + tid;
    int row = idx >> 3, ch = idx & 7;
    uint4 d4 = *(const uint4*)(qb + row * 64 + ch * 8);
    *(uint4*)(&Qs[row * 72 + ch * 8]) = d4;
  }
  __syncthreads();
  // Q fragments (loop-invariant); B operand of S^T = K·Q^T. wave w owns q-strip w*16..+15
  bf16x8 bq0 = *(const bf16x8*)(&Qs[(w * 16 + li) * 72 + quad * 8]);
  bf16x8 bq1 = *(const bf16x8*)(&Qs[(w * 16 + li) * 72 + 32 + quad * 8]);

  f32x4 oacc[4];  // O^T: D[m = d = quad*4+r (+16*dt)][n = q = li]
#pragma unroll
  for (int i = 0; i < 4; ++i)
#pragma unroll
    for (int e = 0; e < 4; ++e) oacc[i][e] = 0.f;
  float m_run = -1e30f, l_run = 0.f;  // per-lane: q = w*16 + li

  int bank = bh % BANKN;
  uint4 kreg[2], vreg[2];
  {
    const u16* kb = kh + (size_t)bh * LQ * 64;
    const u16* vb = vT + (size_t)bh * 64 * LQ;
#pragma unroll
    for (int p = 0; p < 2; ++p) {
      int idx = p * 512 + tid;
      int row = idx >> 3, ch = idx & 7;
      kreg[p] = *(const uint4*)(kb + row * 64 + ch * 8);
    }
#pragma unroll
    for (int p = 0; p < 2; ++p) {
      int idx = p * 512 + tid;
      int row = idx >> 4, ch = idx & 15;
      vreg[p] = *(const uint4*)(vb + (size_t)row * 1024 + ch * 8);
    }
  }

  for (int kt = 0; kt < 10; ++kt) {
    __syncthreads();  // B1: prior iter's Ks(QK) and Vt(PV) reads done
#pragma unroll
    for (int p = 0; p < 2; ++p) {
      int idx = p * 512 + tid;
      int row = idx >> 3, ch = idx & 7;
      *(uint4*)(&Ks[row * 72 + ch * 8]) = kreg[p];
    }
#pragma unroll
    for (int p = 0; p < 2; ++p) {
      int idx = p * 512 + tid;
      int row = idx >> 4, ch = idx & 15;
      *(uint4*)(&Vt[row * 136 + ch * 8]) = vreg[p];
    }
    __syncthreads();  // B2: staging visible

    if (kt < 9) {
      int kn = kt + 1;
      const u16 *kb, *vb;
      int vstride;
      if (kn < 8) {
        kb = kh + ((size_t)bh * LQ + kn * 128) * 64;
        vb = vT + (size_t)bh * 64 * LQ + kn * 128;
        vstride = 1024;
      } else {
        kb = Kp + ((size_t)bank * 256 + (kn - 8) * 128) * 64;
        vb = Vpt + (size_t)bank * 64 * 256 + (kn - 8) * 128;
        vstride = 256;
      }
#pragma unroll
      for (int p = 0; p < 2; ++p) {
        int idx = p * 512 + tid;
        int row = idx >> 3, ch = idx & 7;
        kreg[p] = *(const uint4*)(kb + row * 64 + ch * 8);
      }
#pragma unroll
      for (int p = 0; p < 2; ++p) {
        int idx = p * 512 + tid;
        int row = idx >> 4, ch = idx & 15;
        vreg[p] = *(const uint4*)(vb + (size_t)row * vstride + ch * 8);
      }
    }

    // S^T: lane holds S[q = w*16+li][kt_local = nt*16 + quad*4 + r] (q pre-scaled by 0.125)
    f32x4 sacc[8];
#pragma unroll
    for (int nt = 0; nt < 8; ++nt) {
      bf16x8 k0 = *(const bf16x8*)(&Ks[(nt * 16 + li) * 72 + quad * 8]);
      bf16x8 k1 = *(const bf16x8*)(&Ks[(nt * 16 + li) * 72 + 32 + quad * 8]);
      f32x4 sc;
#pragma unroll
      for (int e = 0; e < 4; ++e) sc[e] = 0.f;
      sc = __builtin_amdgcn_mfma_f32_16x16x32_bf16(k0, bq0, sc, 0, 0, 0);
      sc = __builtin_amdgcn_mfma_f32_16x16x32_bf16(k1, bq1, sc, 0, 0, 0);
      sacc[nt] = sc;
    }

    // online softmax: per-lane scalar state, quad-reduce via 2 shuffles
    float mx = sacc[0][0];
#pragma unroll
    for (int nt = 0; nt < 8; ++nt)
#pragma unroll
      for (int r = 0; r < 4; ++r) mx = fmaxf(mx, sacc[nt][r]);
    mx = fmaxf(mx, __shfl_xor(mx, 16));
    mx = fmaxf(mx, __shfl_xor(mx, 32));
    float mnew = fmaxf(m_run, mx);
    float al = __expf(m_run - mnew);
    m_run = mnew;

    float rsum = 0.f;
    u32 pk[8][2];  // packed bf16 P pairs: pk[nt][h] = (r=2h, r=2h+1)
#pragma unroll
    for (int nt = 0; nt < 8; ++nt) {
      float p0 = __expf(sacc[nt][0] - mnew);
      float p1 = __expf(sacc[nt][1] - mnew);
      float p2 = __expf(sacc[nt][2] - mnew);
      float p3 = __expf(sacc[nt][3] - mnew);
      rsum += (p0 + p1) + (p2 + p3);
      pk[nt][0] = (u32)f2bf(p0) | ((u32)f2bf(p1) << 16);
      pk[nt][1] = (u32)f2bf(p2) | ((u32)f2bf(p3) << 16);
    }
    rsum += __shfl_xor(rsum, 16);
    rsum += __shfl_xor(rsum, 32);
    l_run = l_run * al + rsum;
#pragma unroll
    for (int dt = 0; dt < 4; ++dt)
#pragma unroll
      for (int e = 0; e < 4; ++e) oacc[dt][e] *= al;

    // O^T += Vt · P^T: build P B-frag per 32-k chunk via cross-quad shuffles
    int srcA = ((lane & 16) << 1) + li;  // ((quad&1)*2)*16 + li
    int srcB = srcA + 16;
    bool lowq = (quad < 2);
#pragma unroll
    for (int ks = 0; ks < 4; ++ks) {
      u32 xA0 = __shfl(pk[2 * ks][0], srcA), xA1 = __shfl(pk[2 * ks][1], srcA);
      u32 xB0 = __shfl(pk[2 * ks][0], srcB), xB1 = __shfl(pk[2 * ks][1], srcB);
      u32 yA0 = __shfl(pk[2 * ks + 1][0], srcA), yA1 = __shfl(pk[2 * ks + 1][1], srcA);
      u32 yB0 = __shfl(pk[2 * ks + 1][0], srcB), yB1 = __shfl(pk[2 * ks + 1][1], srcB);
      union { uint4 u; bf16x8 b; } bp;
      bp.u = make_uint4(lowq ? xA0 : yA0, lowq ? xA1 : yA1,
                        lowq ? xB0 : yB0, lowq ? xB1 : yB1);
#pragma unroll
      for (int dt = 0; dt < 4; ++dt) {
        bf16x8 av = *(const bf16x8*)(&Vt[(dt * 16 + li) * 136 + ks * 32 + quad * 8]);
        oacc[dt] = __builtin_amdgcn_mfma_f32_16x16x32_bf16(av, bp.b, oacc[dt], 0, 0, 0);
      }
    }
  }

  // epilogue: O^T[d][q]/l -> stage as OS[q][d] (alias Qs — untouched since pre-loop reads)
  float inv_l = 1.0f / l_run;
#pragma unroll
  for (int dt = 0; dt < 4; ++dt)
#pragma unroll
    for (int r = 0; r < 4; ++r)
      OS[(w * 16 + li) * 72 + dt * 16 + quad * 4 + r] = f2bf(oacc[dt][r] * inv_l);
  __syncthreads();
#pragma unroll
  for (int j = 0; j < 2; ++j) {
    int linear = j * 512 + tid;
    int row = linear >> 3, ci = linear & 7;
    uint4 val = *(const uint4*)(&OS[row * 72 + ci * 8]);
    *(uint4*)(&ctx[((size_t)b * LQ + qt8 * 128 + row) * CDIM + h * 64 + ci * 8]) = val;
  }
}

// ---------- output GEMM: ctx[4096][1280] @ Wo + bo -> out fp32 ----------
__global__ __launch_bounds__(256) void k_gemm_out(const u16* __restrict__ A,
                                                  const u16* __restrict__ Bt,
                                                  const float* __restrict__ bias,
                                                  float* __restrict__ out) {
  __shared__ __align__(16) u16 smem[8192];
  u16* As = smem;
  u16* Bs = smem + 4096;

  int lid = blockIdx.x;            // 0..319
  int s = lid & 7, g = lid >> 3;   // 0..39
  int blkM = s * 4 + (g & 3);
  int blkN = g >> 2;               // 0..9
  int tid = threadIdx.x;
  int lane = tid & 63, quad = lane >> 4, li = lane & 15;
  int w = tid >> 6;
  int wr = w >> 1, wc = w & 1;
  int lrow = lane >> 2, lch = lane & 3;

  f32x4 acc[4][4];
#pragma unroll
  for (int i = 0; i < 4; ++i)
#pragma unroll
    for (int j = 0; j < 4; ++j)
#pragma unroll
      for (int e = 0; e < 4; ++e) acc[i][j][e] = 0.f;

  const u16* Ab = A + (size_t)blkM * 128 * CDIM;
  const u16* Bb = Bt + (size_t)blkN * 128 * CDIM;

  for (int kt = 0; kt < 40; ++kt) {
    __syncthreads();
#pragma unroll
    for (int p = 0; p < 2; ++p) {
      int row = p * 64 + w * 16;
      async16(As + row * 32, Ab + (size_t)(row + lrow) * CDIM + kt * 32 + lch * 8);
      async16(Bs + row * 32, Bb + (size_t)(row + lrow) * CDIM + kt * 32 + lch * 8);
    }
    __syncthreads();
    bf16x8 af[4], bfr[4];
#pragma unroll
    for (int mt = 0; mt < 4; ++mt)
      af[mt] = *(const bf16x8*)(As + (wr * 64 + mt * 16 + li) * 32 + quad * 8);
#pragma unroll
    for (int nt = 0; nt < 4; ++nt)
      bfr[nt] = *(const bf16x8*)(Bs + (wc * 64 + nt * 16 + li) * 32 + quad * 8);
#pragma unroll
    for (int mt = 0; mt < 4; ++mt)
#pragma unroll
      for (int nt = 0; nt < 4; ++nt)
        acc[mt][nt] = __builtin_amdgcn_mfma_f32_16x16x32_bf16(af[mt], bfr[nt], acc[mt][nt], 0, 0, 0);
  }

#pragma unroll
  for (int mt = 0; mt < 4; ++mt) {
#pragma unroll
    for (int nt = 0; nt < 4; ++nt) {
#pragma unroll
      for (int r = 0; r < 4; ++r) {
        int row = blkM * 128 + wr * 64 + mt * 16 + quad * 4 + r;
        int col = blkN * 128 + wc * 64 + nt * 16 + li;
        out[(size_t)row * CDIM + col] = acc[mt][nt][r] + bias[col];
      }
    }
  }
}

extern "C" void kernel_launch(void* const* d_in, const int* in_sizes, int n_in,
                              void* d_out, int out_size, void* d_ws, size_t ws_size,
                              hipStream_t stream) {
  const float* X = (const float*)d_in[0];
  const float* Wq = (const float*)d_in[1];
  const float* Wk = (const float*)d_in[2];
  const float* Wv = (const float*)d_in[3];
  const float* Wo = (const float*)d_in[4];
  const float* bo = (const float*)d_in[5];
  const float* Kbg = (const float*)d_in[6];
  const float* Vbg = (const float*)d_in[7];

  char* ws = (char*)d_ws;
  u16* Xb    = (u16*)(ws + 0);          // 4096*1280*2  = 10485760
  u16* Wtqkv = (u16*)(ws + 10485760);   // 3*1280*1280*2 = 9830400
  u16* Wot   = (u16*)(ws + 20316160);   // 1280*1280*2  = 3276800
  u16* qh    = (u16*)(ws + 23592960);   // 80*1024*64*2 = 10485760
  u16* kh    = (u16*)(ws + 34078720);
  u16* vT    = (u16*)(ws + 55050240);
  u16* Kp    = (u16*)(ws + 65536000);   // 40*256*64*2 = 1310720
  u16* Vpt   = (u16*)(ws + 66846720);
  u16* ctx   = (u16*)(ws + 68157440);   // ends 78643200
  if (ws_size < 78643200) return;

  float* out = (float*)d_out;

  k_convx<<<5120, 256, 0, stream>>>(X, Xb);
  k_wtrans<<<dim3(40, 40, 4), dim3(32, 8), 0, stream>>>(Wq, Wk, Wv, Wo, Wtqkv, Wot);
  k_pool<<<dim3(40, 4), 256, 0, stream>>>(Kbg, Vbg, Kp, Vpt);
  k_gemm_qkv<<<960, 256, 0, stream>>>(Xb, Wtqkv, qh, kh, vT);
  k_attn<<<640, 512, 0, stream>>>(qh, kh, vT, Kp, Vpt, ctx);
  k_gemm_out<<<320, 256, 0, stream>>>(ctx, Wot, bo, out);
}

// Round 11
// 317.695 us; speedup vs baseline: 1.1275x; 1.0254x over previous
//
#include <hip/hip_runtime.h>
#include <hip/hip_fp16.h>

// Problem constants
#define CDIM 1280
#define LQ 1024
#define NH 20
#define BANKN 40
#define ALPHA_SC 0.48f
#define VTS 140   // Vt LDS row stride (u16): 70 words == 6 mod 32 -> conflict-free b64/b128, 8B aligned

typedef __bf16 bf16x8 __attribute__((ext_vector_type(8)));
typedef float f32x4 __attribute__((ext_vector_type(4)));
typedef short s16x4 __attribute__((ext_vector_type(4)));
typedef unsigned short u16;
typedef unsigned int u32;

// 16x16x16 bf16 MFMA: B[k=quad*4+j][n=li] matches S^T's C/D layout exactly -> P needs no shuffle.
#if __has_builtin(__builtin_amdgcn_mfma_f32_16x16x16bf16_1k)
#define HAVE_MFMA16 1
__device__ __forceinline__ f32x4 mfma16(s16x4 a, s16x4 b, f32x4 c) {
  return __builtin_amdgcn_mfma_f32_16x16x16bf16_1k(a, b, c, 0, 0, 0);
}
#elif __has_builtin(__builtin_amdgcn_mfma_f32_16x16x16_bf16)
#define HAVE_MFMA16 1
typedef __bf16 bf16x4 __attribute__((ext_vector_type(4)));
__device__ __forceinline__ f32x4 mfma16(s16x4 a, s16x4 b, f32x4 c) {
  union { s16x4 s; bf16x4 b; } ua, ub;
  ua.s = a; ub.s = b;
  return __builtin_amdgcn_mfma_f32_16x16x16_bf16(ua.b, ub.b, c, 0, 0, 0);
}
#else
#define HAVE_MFMA16 0
#endif

__device__ __forceinline__ u16 f2bf(float f) {
  union { float f; u32 u; } v; v.f = f;
  u32 r = v.u + 0x7fffu + ((v.u >> 16) & 1u);
  return (u16)(r >> 16);
}

__device__ __forceinline__ void async16(void* lds, const void* g) {
  __builtin_amdgcn_global_load_lds(
      (const __attribute__((address_space(1))) unsigned int*)g,
      (__attribute__((address_space(3))) unsigned int*)lds,
      16, 0, 0);
}

// ---------- prep: fp32 -> bf16 convert of hidden_states ----------
__global__ __launch_bounds__(256) void k_convx(const float* __restrict__ X,
                                               u16* __restrict__ Xb) {
  int i = (blockIdx.x * 256 + threadIdx.x) * 4;
  float4 f = *(const float4*)(X + i);
  u32 lo = (u32)f2bf(f.x) | ((u32)f2bf(f.y) << 16);
  u32 hi = (u32)f2bf(f.z) | ((u32)f2bf(f.w) << 16);
  *(uint2*)(Xb + i) = make_uint2(lo, hi);
}

// ---------- prep: transpose+convert weights: Wt[n][k] = W[k][n] ----------
__global__ __launch_bounds__(256) void k_wtrans(const float* __restrict__ Wq,
                                                const float* __restrict__ Wk,
                                                const float* __restrict__ Wv,
                                                const float* __restrict__ Wo,
                                                u16* __restrict__ Wtqkv,
                                                u16* __restrict__ Wot) {
  __shared__ float tile[32][33];
  int z = blockIdx.z;
  const float* src = (z == 0) ? Wq : (z == 1) ? Wk : (z == 2) ? Wv : Wo;
  u16* dst = (z < 3) ? (Wtqkv + (size_t)z * CDIM * CDIM) : Wot;
  int tx = threadIdx.x, ty = threadIdx.y;
  int n0 = blockIdx.x * 32, k0 = blockIdx.y * 32;
#pragma unroll
  for (int j = 0; j < 4; ++j)
    tile[ty + 8 * j][tx] = src[(size_t)(k0 + ty + 8 * j) * CDIM + n0 + tx];
  __syncthreads();
#pragma unroll
  for (int j = 0; j < 4; ++j)
    dst[(size_t)(n0 + ty + 8 * j) * CDIM + k0 + tx] = f2bf(tile[tx][ty + 8 * j]);
}

// ---------- prep: bank KV fp16-round + 2x2 avg-pool + alpha ----------
__global__ __launch_bounds__(256) void k_pool(const float* __restrict__ Kbg,
                                              const float* __restrict__ Vbg,
                                              u16* __restrict__ Kp,
                                              u16* __restrict__ Vpt) {
  int bank = blockIdx.x, seg = blockIdx.y;
  int tid = threadIdx.x;
#pragma unroll
  for (int j = 0; j < 16; ++j) {
    int idx = j * 256 + tid;
    int d = idx & 63, tl = idx >> 6;
    int t = seg * 64 + tl;
    int r = t >> 4, c = t & 15;
    int tok = (r * 2) * 32 + c * 2;
    const float* kb = Kbg + ((size_t)bank * 1024 + tok) * 64 + d;
    float k0 = __half2float(__float2half(kb[0]));
    float k1 = __half2float(__float2half(kb[64]));
    float k2 = __half2float(__float2half(kb[32 * 64]));
    float k3 = __half2float(__float2half(kb[33 * 64]));
    Kp[((size_t)bank * 256 + t) * 64 + d] = f2bf((k0 + k1 + k2 + k3) * 0.25f * ALPHA_SC);
  }
#pragma unroll
  for (int j = 0; j < 16; ++j) {
    int idx = j * 256 + tid;
    int tl = idx & 63, d = idx >> 6;
    int t = seg * 64 + tl;
    int r = t >> 4, c = t & 15;
    int tok = (r * 2) * 32 + c * 2;
    const float* vb = Vbg + ((size_t)bank * 1024 + tok) * 64 + d;
    float v0 = __half2float(__float2half(vb[0]));
    float v1 = __half2float(__float2half(vb[64]));
    float v2 = __half2float(__float2half(vb[32 * 64]));
    float v3 = __half2float(__float2half(vb[33 * 64]));
    Vpt[((size_t)bank * 64 + d) * 256 + t] = f2bf((v0 + v1 + v2 + v3) * 0.25f * ALPHA_SC);
  }
}

// ---------- QKV GEMM: Xb[4096][1280] @ {Wq,Wk,Wv}^T -> qh/kh [80][1024][64], vT [80][64][1024] ----------
// m97 structure: BK=32, global_load_lds width=16, XCD swizzle. q is pre-scaled by 0.125 (exact in bf16).
__global__ __launch_bounds__(256) void k_gemm_qkv(const u16* __restrict__ A,
                                                  const u16* __restrict__ Bt,
                                                  u16* __restrict__ qh,
                                                  u16* __restrict__ kh,
                                                  u16* __restrict__ vT) {
  __shared__ __align__(16) u16 smem[8704];  // K-loop: As[4096]+Bs[4096]; epilogue alias OS[64*136]
  u16* As = smem;
  u16* Bs = smem + 4096;
  u16* OS = smem;

  int lid = blockIdx.x;            // 0..959
  int s = lid & 7, g = lid >> 3;   // XCD swizzle: same-XCD blocks share A-panels
  int blkM = s * 4 + (g & 3);      // 0..31
  int blkN = g >> 2;               // 0..29
  int tid = threadIdx.x;
  int lane = tid & 63, quad = lane >> 4, li = lane & 15;
  int w = tid >> 6;
  int wr = w >> 1, wc = w & 1;
  int lrow = lane >> 2, lch = lane & 3;

  f32x4 acc[4][4];
#pragma unroll
  for (int i = 0; i < 4; ++i)
#pragma unroll
    for (int j = 0; j < 4; ++j)
#pragma unroll
      for (int e = 0; e < 4; ++e) acc[i][j][e] = 0.f;

  const u16* Ab = A + (size_t)blkM * 128 * CDIM;
  const u16* Bb = Bt + (size_t)blkN * 128 * CDIM;

  for (int kt = 0; kt < 40; ++kt) {
    __syncthreads();  // prior iter's ds_reads done before DMA overwrite
#pragma unroll
    for (int p = 0; p < 2; ++p) {
      int row = p * 64 + w * 16;  // wave-uniform LDS base
      async16(As + row * 32, Ab + (size_t)(row + lrow) * CDIM + kt * 32 + lch * 8);
      async16(Bs + row * 32, Bb + (size_t)(row + lrow) * CDIM + kt * 32 + lch * 8);
    }
    __syncthreads();  // vmcnt(0) drain makes DMA writes visible
    bf16x8 af[4], bfr[4];
#pragma unroll
    for (int mt = 0; mt < 4; ++mt)
      af[mt] = *(const bf16x8*)(As + (wr * 64 + mt * 16 + li) * 32 + quad * 8);
#pragma unroll
    for (int nt = 0; nt < 4; ++nt)
      bfr[nt] = *(const bf16x8*)(Bs + (wc * 64 + nt * 16 + li) * 32 + quad * 8);
#pragma unroll
    for (int mt = 0; mt < 4; ++mt)
#pragma unroll
      for (int nt = 0; nt < 4; ++nt)
        acc[mt][nt] = __builtin_amdgcn_mfma_f32_16x16x32_bf16(af[mt], bfr[nt], acc[mt][nt], 0, 0, 0);
  }

  int which = blkN / 10;  // 0=q 1=k 2=v
  float osc = (which == 0) ? 0.125f : 1.0f;  // fold 1/sqrt(Dh) into q (exact: power of 2)
  int cbase = (blkN % 10) * 128;
  int b = blkM >> 3;  // 128 rows lie within one batch
#pragma unroll
  for (int p = 0; p < 2; ++p) {
    __syncthreads();
    if (wr == p) {
#pragma unroll
      for (int mt = 0; mt < 4; ++mt)
#pragma unroll
        for (int nt = 0; nt < 4; ++nt)
#pragma unroll
          for (int r = 0; r < 4; ++r)
            OS[(mt * 16 + quad * 4 + r) * 136 + wc * 64 + nt * 16 + li] = f2bf(acc[mt][nt][r] * osc);
    }
    __syncthreads();
    if (which < 2) {
      u16* dst = (which == 0) ? qh : kh;
#pragma unroll
      for (int j = 0; j < 4; ++j) {
        int linear = j * 256 + tid;
        int row = linear >> 4, ci = linear & 15;
        int grow = blkM * 128 + p * 64 + row;
        int l = grow & 1023;
        int c = cbase + ci * 8;
        int h = c >> 6, dd = c & 63;
        uint4 val = *(const uint4*)(&OS[row * 136 + ci * 8]);
        *(uint4*)(&dst[(((size_t)(b * NH + h)) * LQ + l) * 64 + dd]) = val;
      }
    } else {
      // v: write transposed directly into vT[80][64][1024]
      int vrow = tid >> 1;
      int lhalf = tid & 1;
      int h = (cbase + vrow) >> 6, d = vrow & 63;
      size_t vbase = (((size_t)(b * NH + h)) * 64 + d) * LQ +
                     (blkM & 7) * 128 + p * 64 + lhalf * 32;
#pragma unroll
      for (int c4 = 0; c4 < 4; ++c4) {
        int ll = lhalf * 32 + c4 * 8;
        u32 w0 = (u32)OS[(ll + 0) * 136 + vrow] | ((u32)OS[(ll + 1) * 136 + vrow] << 16);
        u32 w1 = (u32)OS[(ll + 2) * 136 + vrow] | ((u32)OS[(ll + 3) * 136 + vrow] << 16);
        u32 w2 = (u32)OS[(ll + 4) * 136 + vrow] | ((u32)OS[(ll + 5) * 136 + vrow] << 16);
        u32 w3 = (u32)OS[(ll + 6) * 136 + vrow] | ((u32)OS[(ll + 7) * 136 + vrow] << 16);
        *(uint4*)(vT + vbase + c4 * 8) = make_uint4(w0, w1, w2, w3);
      }
    }
  }
}

// ---------- flash attention, transposed-S form, 128-q blocks (512 thr / 8 waves) ----------
// PV via v_mfma_f32_16x16x16_bf16: S^T's C/D layout IS the 16x16x16 B-operand layout,
// so P feeds PV directly from registers — the 32 ds_bpermute/iter of round 10 are gone.
// Vt A-frags come from 32 ds_read_b64/iter (stride 140 u16: conflict-free, 8B-aligned).
__global__ __launch_bounds__(512)
__attribute__((amdgpu_waves_per_eu(4, 4)))
void k_attn(const u16* __restrict__ qh,
            const u16* __restrict__ kh,
            const u16* __restrict__ vT,
            const u16* __restrict__ Kp,
            const u16* __restrict__ Vpt,
            u16* __restrict__ ctx) {
  __shared__ u16 Qs[128 * 72];   // Q tile; epilogue alias OS[128][72]
  __shared__ u16 Ks[128 * 72];
  __shared__ u16 Vt[64 * VTS];
  u16* OS = Qs;
  int lid = blockIdx.x;            // 0..639
  int s = lid & 7, g = lid >> 3;   // XCD swizzle: XCD s owns bh range [s*10, s*10+10)
  int bh = s * 10 + (g >> 3);
  int qt8 = g & 7;                 // 128-row q tile
  int b = bh / NH, h = bh % NH;
  int tid = threadIdx.x;
  int w = tid >> 6, lane = tid & 63, quad = lane >> 4, li = lane & 15;

  const u16* qb = qh + ((size_t)bh * LQ + qt8 * 128) * 64;
#pragma unroll
  for (int p = 0; p < 2; ++p) {
    int idx = p * 512 + tid;
    int row = idx >> 3, ch = idx & 7;
    uint4 d4 = *(const uint4*)(qb + row * 64 + ch * 8);
    *(uint4*)(&Qs[row * 72 + ch * 8]) = d4;
  }
  __syncthreads();
  // Q fragments (loop-invariant); B operand of S^T = K·Q^T. wave w owns q-strip w*16..+15
  bf16x8 bq0 = *(const bf16x8*)(&Qs[(w * 16 + li) * 72 + quad * 8]);
  bf16x8 bq1 = *(const bf16x8*)(&Qs[(w * 16 + li) * 72 + 32 + quad * 8]);

  f32x4 oacc[4];  // O^T: D[m = d = quad*4+r (+16*dt)][n = q = li]
#pragma unroll
  for (int i = 0; i < 4; ++i)
#pragma unroll
    for (int e = 0; e < 4; ++e) oacc[i][e] = 0.f;
  float m_run = -1e30f, l_run = 0.f;  // per-lane: q = w*16 + li

  int bank = bh % BANKN;
  uint4 kreg[2], vreg[2];
  {
    const u16* kb = kh + (size_t)bh * LQ * 64;
    const u16* vb = vT + (size_t)bh * 64 * LQ;
#pragma unroll
    for (int p = 0; p < 2; ++p) {
      int idx = p * 512 + tid;
      int row = idx >> 3, ch = idx & 7;
      kreg[p] = *(const uint4*)(kb + row * 64 + ch * 8);
    }
#pragma unroll
    for (int p = 0; p < 2; ++p) {
      int idx = p * 512 + tid;
      int row = idx >> 4, ch = idx & 15;
      vreg[p] = *(const uint4*)(vb + (size_t)row * 1024 + ch * 8);
    }
  }

  for (int kt = 0; kt < 10; ++kt) {
    __syncthreads();  // B1: prior iter's Ks(QK) and Vt(PV) reads done
#pragma unroll
    for (int p = 0; p < 2; ++p) {
      int idx = p * 512 + tid;
      int row = idx >> 3, ch = idx & 7;
      *(uint4*)(&Ks[row * 72 + ch * 8]) = kreg[p];
    }
#pragma unroll
    for (int p = 0; p < 2; ++p) {
      int idx = p * 512 + tid;
      int row = idx >> 4, ch = idx & 15;
      *(uint4*)(&Vt[row * VTS + ch * 8]) = vreg[p];
    }
    __syncthreads();  // B2: staging visible

    if (kt < 9) {
      int kn = kt + 1;
      const u16 *kb, *vb;
      int vstride;
      if (kn < 8) {
        kb = kh + ((size_t)bh * LQ + kn * 128) * 64;
        vb = vT + (size_t)bh * 64 * LQ + kn * 128;
        vstride = 1024;
      } else {
        kb = Kp + ((size_t)bank * 256 + (kn - 8) * 128) * 64;
        vb = Vpt + (size_t)bank * 64 * 256 + (kn - 8) * 128;
        vstride = 256;
      }
#pragma unroll
      for (int p = 0; p < 2; ++p) {
        int idx = p * 512 + tid;
        int row = idx >> 3, ch = idx & 7;
        kreg[p] = *(const uint4*)(kb + row * 64 + ch * 8);
      }
#pragma unroll
      for (int p = 0; p < 2; ++p) {
        int idx = p * 512 + tid;
        int row = idx >> 4, ch = idx & 15;
        vreg[p] = *(const uint4*)(vb + (size_t)row * vstride + ch * 8);
      }
    }

    // S^T: lane holds S[q = w*16+li][kt_local = nt*16 + quad*4 + r] (q pre-scaled by 0.125)
    f32x4 sacc[8];
#pragma unroll
    for (int nt = 0; nt < 8; ++nt) {
      bf16x8 k0 = *(const bf16x8*)(&Ks[(nt * 16 + li) * 72 + quad * 8]);
      bf16x8 k1 = *(const bf16x8*)(&Ks[(nt * 16 + li) * 72 + 32 + quad * 8]);
      f32x4 sc;
#pragma unroll
      for (int e = 0; e < 4; ++e) sc[e] = 0.f;
      sc = __builtin_amdgcn_mfma_f32_16x16x32_bf16(k0, bq0, sc, 0, 0, 0);
      sc = __builtin_amdgcn_mfma_f32_16x16x32_bf16(k1, bq1, sc, 0, 0, 0);
      sacc[nt] = sc;
    }

    // online softmax: per-lane scalar state, quad-reduce via 2 shuffles
    float mx = sacc[0][0];
#pragma unroll
    for (int nt = 0; nt < 8; ++nt)
#pragma unroll
      for (int r = 0; r < 4; ++r) mx = fmaxf(mx, sacc[nt][r]);
    mx = fmaxf(mx, __shfl_xor(mx, 16));
    mx = fmaxf(mx, __shfl_xor(mx, 32));
    float mnew = fmaxf(m_run, mx);
    float al = __expf(m_run - mnew);
    m_run = mnew;

    float rsum = 0.f;
    u32 pk[8][2];  // packed bf16 P pairs: pk[nt][h] = (r=2h, r=2h+1)
#pragma unroll
    for (int nt = 0; nt < 8; ++nt) {
      float p0 = __expf(sacc[nt][0] - mnew);
      float p1 = __expf(sacc[nt][1] - mnew);
      float p2 = __expf(sacc[nt][2] - mnew);
      float p3 = __expf(sacc[nt][3] - mnew);
      rsum += (p0 + p1) + (p2 + p3);
      pk[nt][0] = (u32)f2bf(p0) | ((u32)f2bf(p1) << 16);
      pk[nt][1] = (u32)f2bf(p2) | ((u32)f2bf(p3) << 16);
    }
    rsum += __shfl_xor(rsum, 16);
    rsum += __shfl_xor(rsum, 32);
    l_run = l_run * al + rsum;
#pragma unroll
    for (int dt = 0; dt < 4; ++dt)
#pragma unroll
      for (int e = 0; e < 4; ++e) oacc[dt][e] *= al;

#if HAVE_MFMA16
    // O^T += Vt · P^T via 16x16x16: P (pk) is already the B operand; A = Vt b64 reads.
#pragma unroll
    for (int dt = 0; dt < 4; ++dt) {
      const u16* vrow = &Vt[(dt * 16 + li) * VTS + quad * 4];
#pragma unroll
      for (int nt = 0; nt < 8; ++nt) {
        union { uint2 u; s16x4 s; } av;
        av.u = *(const uint2*)(vrow + nt * 16);
        union { u32 u[2]; s16x4 s; } bp;
        bp.u[0] = pk[nt][0];
        bp.u[1] = pk[nt][1];
        oacc[dt] = mfma16(av.s, bp.s, oacc[dt]);
      }
    }
#else
    // fallback: cross-quad shuffle into 16x16x32 B-frags (round-10 path)
    int srcA = ((lane & 16) << 1) + li;
    int srcB = srcA + 16;
    bool lowq = (quad < 2);
#pragma unroll
    for (int ks = 0; ks < 4; ++ks) {
      u32 xA0 = __shfl(pk[2 * ks][0], srcA), xA1 = __shfl(pk[2 * ks][1], srcA);
      u32 xB0 = __shfl(pk[2 * ks][0], srcB), xB1 = __shfl(pk[2 * ks][1], srcB);
      u32 yA0 = __shfl(pk[2 * ks + 1][0], srcA), yA1 = __shfl(pk[2 * ks + 1][1], srcA);
      u32 yB0 = __shfl(pk[2 * ks + 1][0], srcB), yB1 = __shfl(pk[2 * ks + 1][1], srcB);
      union { uint4 u; bf16x8 b; } bp;
      bp.u = make_uint4(lowq ? xA0 : yA0, lowq ? xA1 : yA1,
                        lowq ? xB0 : yB0, lowq ? xB1 : yB1);
#pragma unroll
      for (int dt = 0; dt < 4; ++dt) {
        bf16x8 av = *(const bf16x8*)(&Vt[(dt * 16 + li) * VTS + ks * 32 + quad * 8]);
        oacc[dt] = __builtin_amdgcn_mfma_f32_16x16x32_bf16(av, bp.b, oacc[dt], 0, 0, 0);
      }
    }
#endif
  }

  // epilogue: O^T[d][q]/l -> stage as OS[q][d] (alias Qs — untouched since pre-loop reads)
  float inv_l = 1.0f / l_run;
#pragma unroll
  for (int dt = 0; dt < 4; ++dt)
#pragma unroll
    for (int r = 0; r < 4; ++r)
      OS[(w * 16 + li) * 72 + dt * 16 + quad * 4 + r] = f2bf(oacc[dt][r] * inv_l);
  __syncthreads();
#pragma unroll
  for (int j = 0; j < 2; ++j) {
    int linear = j * 512 + tid;
    int row = linear >> 3, ci = linear & 7;
    uint4 val = *(const uint4*)(&OS[row * 72 + ci * 8]);
    *(uint4*)(&ctx[((size_t)b * LQ + qt8 * 128 + row) * CDIM + h * 64 + ci * 8]) = val;
  }
}

// ---------- output GEMM: ctx[4096][1280] @ Wo + bo -> out fp32 ----------
__global__ __launch_bounds__(256) void k_gemm_out(const u16* __restrict__ A,
                                                  const u16* __restrict__ Bt,
                                                  const float* __restrict__ bias,
                                                  float* __restrict__ out) {
  __shared__ __align__(16) u16 smem[8192];
  u16* As = smem;
  u16* Bs = smem + 4096;

  int lid = blockIdx.x;            // 0..319
  int s = lid & 7, g = lid >> 3;   // 0..39
  int blkM = s * 4 + (g & 3);
  int blkN = g >> 2;               // 0..9
  int tid = threadIdx.x;
  int lane = tid & 63, quad = lane >> 4, li = lane & 15;
  int w = tid >> 6;
  int wr = w >> 1, wc = w & 1;
  int lrow = lane >> 2, lch = lane & 3;

  f32x4 acc[4][4];
#pragma unroll
  for (int i = 0; i < 4; ++i)
#pragma unroll
    for (int j = 0; j < 4; ++j)
#pragma unroll
      for (int e = 0; e < 4; ++e) acc[i][j][e] = 0.f;

  const u16* Ab = A + (size_t)blkM * 128 * CDIM;
  const u16* Bb = Bt + (size_t)blkN * 128 * CDIM;

  for (int kt = 0; kt < 40; ++kt) {
    __syncthreads();
#pragma unroll
    for (int p = 0; p < 2; ++p) {
      int row = p * 64 + w * 16;
      async16(As + row * 32, Ab + (size_t)(row + lrow) * CDIM + kt * 32 + lch * 8);
      async16(Bs + row * 32, Bb + (size_t)(row + lrow) * CDIM + kt * 32 + lch * 8);
    }
    __syncthreads();
    bf16x8 af[4], bfr[4];
#pragma unroll
    for (int mt = 0; mt < 4; ++mt)
      af[mt] = *(const bf16x8*)(As + (wr * 64 + mt * 16 + li) * 32 + quad * 8);
#pragma unroll
    for (int nt = 0; nt < 4; ++nt)
      bfr[nt] = *(const bf16x8*)(Bs + (wc * 64 + nt * 16 + li) * 32 + quad * 8);
#pragma unroll
    for (int mt = 0; mt < 4; ++mt)
#pragma unroll
      for (int nt = 0; nt < 4; ++nt)
        acc[mt][nt] = __builtin_amdgcn_mfma_f32_16x16x32_bf16(af[mt], bfr[nt], acc[mt][nt], 0, 0, 0);
  }

#pragma unroll
  for (int mt = 0; mt < 4; ++mt) {
#pragma unroll
    for (int nt = 0; nt < 4; ++nt) {
#pragma unroll
      for (int r = 0; r < 4; ++r) {
        int row = blkM * 128 + wr * 64 + mt * 16 + quad * 4 + r;
        int col = blkN * 128 + wc * 64 + nt * 16 + li;
        out[(size_t)row * CDIM + col] = acc[mt][nt][r] + bias[col];
      }
    }
  }
}

extern "C" void kernel_launch(void* const* d_in, const int* in_sizes, int n_in,
                              void* d_out, int out_size, void* d_ws, size_t ws_size,
                              hipStream_t stream) {
  const float* X = (const float*)d_in[0];
  const float* Wq = (const float*)d_in[1];
  const float* Wk = (const float*)d_in[2];
  const float* Wv = (const float*)d_in[3];
  const float* Wo = (const float*)d_in[4];
  const float* bo = (const float*)d_in[5];
  const float* Kbg = (const float*)d_in[6];
  const float* Vbg = (const float*)d_in[7];

  char* ws = (char*)d_ws;
  u16* Xb    = (u16*)(ws + 0);          // 4096*1280*2  = 10485760
  u16* Wtqkv = (u16*)(ws + 10485760);   // 3*1280*1280*2 = 9830400
  u16* Wot   = (u16*)(ws + 20316160);   // 1280*1280*2  = 3276800
  u16* qh    = (u16*)(ws + 23592960);   // 80*1024*64*2 = 10485760
  u16* kh    = (u16*)(ws + 34078720);
  u16* vT    = (u16*)(ws + 55050240);
  u16* Kp    = (u16*)(ws + 65536000);   // 40*256*64*2 = 1310720
  u16* Vpt   = (u16*)(ws + 66846720);
  u16* ctx   = (u16*)(ws + 68157440);   // ends 78643200
  if (ws_size < 78643200) return;

  float* out = (float*)d_out;

  k_convx<<<5120, 256, 0, stream>>>(X, Xb);
  k_wtrans<<<dim3(40, 40, 4), dim3(32, 8), 0, stream>>>(Wq, Wk, Wv, Wo, Wtqkv, Wot);
  k_pool<<<dim3(40, 4), 256, 0, stream>>>(Kbg, Vbg, Kp, Vpt);
  k_gemm_qkv<<<960, 256, 0, stream>>>(Xb, Wtqkv, qh, kh, vT);
  k_attn<<<640, 512, 0, stream>>>(qh, kh, vT, Kp, Vpt, ctx);
  k_gemm_out<<<320, 256, 0, stream>>>(ctx, Wot, bo, out);
}